// Round 11
// baseline (415.617 us; speedup 1.0000x reference)
//
#include <hip/hip_runtime.h>

typedef __attribute__((ext_vector_type(8))) short bfrag8;   // 8 bf16 = 4 VGPRs
typedef __attribute__((ext_vector_type(4))) float f32x4v;   // MFMA acc / nt stores
typedef __attribute__((ext_vector_type(4))) int   i32x4v;   // nt stores

__device__ inline short f2bf(float f) {
    unsigned u = __builtin_bit_cast(unsigned, f);
    u = (u + 0x7FFFu + ((u >> 16) & 1u)) >> 16;
    return (short)u;
}
__device__ inline float bf2f(short s) {
    unsigned u = ((unsigned)(unsigned short)s) << 16;
    return __builtin_bit_cast(float, u);
}
__device__ inline int pack2(short lo, short hi) {
    return (int)(((unsigned)(unsigned short)lo) | (((unsigned)(unsigned short)hi) << 16));
}
__device__ inline int pad16i(int v) { return (v + 15) & ~15; }

// ---------------- CSR construction ----------------
// Self-loops folded in (self entry first); each list zero-padded to a multiple
// of 16 with entries pointing at row n (a guaranteed-zero row of the tables).
// R5: scatter/atomic kernels want 1 edge/thread + PLAIN stores.
// R8/R9: gather kernels need one-wave-per-node, barrier-free.
// R10: co-tenant resources throttle the atomic pole -> keep co-tenant small.

__global__ void block_sum_kernel(const int* __restrict__ deg, int n, int* __restrict__ bsums) {
    int i = blockIdx.x * 256 + threadIdx.x;
    int v = (i < n) ? pad16i(deg[i] + 1) : 0;   // +1 self, padded
#pragma unroll
    for (int off = 32; off > 0; off >>= 1) v += __shfl_down(v, off);
    __shared__ int wsum[4];
    int lane = threadIdx.x & 63, w = threadIdx.x >> 6;
    if (lane == 0) wsum[w] = v;
    __syncthreads();
    if (threadIdx.x == 0) bsums[blockIdx.x] = wsum[0] + wsum[1] + wsum[2] + wsum[3];
}

// Fused: every block redundantly scans the (<=256) block sums in LDS, then
// scans its own 256 padded degrees and emits offs/cursor/dinv/csr-pads.
__global__ void scan_final_kernel(const int* __restrict__ deg, int n, int B,
                                  const int* __restrict__ bsums,
                                  int* __restrict__ offs, int* __restrict__ cursor,
                                  float* __restrict__ dinv, int* __restrict__ csr) {
    __shared__ int sb[256];
    __shared__ int s[256];
    int tid = threadIdx.x;
    sb[tid] = (tid < B) ? bsums[tid] : 0;
    __syncthreads();
    for (int off = 1; off < 256; off <<= 1) {
        int t = (tid >= off) ? sb[tid - off] : 0;
        __syncthreads();
        sb[tid] += t;
        __syncthreads();
    }
    int myBase = (blockIdx.x == 0) ? 0 : sb[blockIdx.x - 1];
    int total = sb[255];
    int i = blockIdx.x * 256 + tid;
    int vt = (i < n) ? deg[i] + 1 : 0;          // true count incl. self
    int pv = (i < n) ? pad16i(vt) : 0;          // padded count
    s[tid] = pv;
    __syncthreads();
    for (int off = 1; off < 256; off <<= 1) {
        int t = (tid >= off) ? s[tid - off] : 0;
        __syncthreads();
        s[tid] += t;
        __syncthreads();
    }
    if (i < n) {
        int excl = s[tid] - pv + myBase;
        offs[i] = excl;
        csr[excl] = i;                           // self-loop first
        cursor[i] = excl + 1;
        for (int p = excl + vt; p < excl + pv; ++p) csr[p] = n;  // zero-row pads
        dinv[i] = rsqrtf((float)vt);
    } else if (i < gridDim.x * 256) {
        dinv[i] = 0.f;                           // pad rows: zero (kills t pads)
    }
    if (blockIdx.x == 0 && tid == 0) offs[n] = total;
}

// ---------------- fused prep: deg_count + x->bf16 (+ zero pads) + W transpose ----------------

__global__ void prep_kernel(const int* __restrict__ dst, int E, int* __restrict__ deg,
                            const float* __restrict__ x, short* __restrict__ xb,
                            int total8, int totalp8,
                            const float* __restrict__ W1, short* __restrict__ Wt1,
                            const float* __restrict__ W2, short* __restrict__ Wt2,
                            const float* __restrict__ W3, short* __restrict__ Wt3) {
    int g = blockIdx.x * blockDim.x + threadIdx.x;
    if (g < E) {
        atomicAdd(&deg[dst[g]], 1);
        return;
    }
    int i = g - E;
    if (i < total8) {
        const float4* p = (const float4*)(x + (size_t)i * 8);
        float4 v0 = p[0], v1 = p[1];
        int4 w = make_int4(pack2(f2bf(v0.x), f2bf(v0.y)), pack2(f2bf(v0.z), f2bf(v0.w)),
                           pack2(f2bf(v1.x), f2bf(v1.y)), pack2(f2bf(v1.z), f2bf(v1.w)));
        *(int4*)(xb + (size_t)i * 8) = w;
    } else if (i < totalp8) {
        *(int4*)(xb + (size_t)i * 8) = make_int4(0, 0, 0, 0);
    } else {
        int j = i - totalp8;
        if (j < 65536) {                       // W1: K=256, N=256
            int k = j >> 8, c = j & 255;
            Wt1[c * 256 + k] = f2bf(W1[j]);
        } else if (j < 65536 + 32768) {        // W2: K=256, N=128
            int m = j - 65536;
            int k = m >> 7, c = m & 127;
            Wt2[c * 256 + k] = f2bf(W2[m]);
        } else if (j < 65536 + 32768 + 16384) { // W3: K=128, N=128
            int m = j - 65536 - 32768;
            int k = m >> 7, c = m & 127;
            Wt3[c * 128 + k] = f2bf(W3[m]);
        }
    }
}

// ---------------- GEMM core, BN=128 (XOR-swizzled B tile) — proven shape ----------------
// Used standalone for gemm2/gemm3.

template<int K>
__global__ __launch_bounds__(256, 2) void gemm_skinny_kernel(
        const short* __restrict__ A, const short* __restrict__ Bt,
        const float* __restrict__ dinv, short* __restrict__ Tout, int ldt) {
    __shared__ short Bs[128 * K];
    char* bsb = (char*)Bs;

    const int tid = threadIdx.x;
    const int lane = tid & 63;
    const int wid = tid >> 6;
    const int l15 = lane & 15;
    const int quad = lane >> 4;
    const int q8 = quad * 8;
    const int bn = blockIdx.y * 128;
    const int row0 = blockIdx.x * 256 + wid * 64;

    {
        constexpr int TOT16 = 128 * K / 8;
#pragma unroll
        for (int i = tid; i < TOT16; i += 256) {
            int r = i / (K / 8);
            int c = (i % (K / 8)) * 8;
            int byteoff = (r * K + c) * 2;
            byteoff ^= (r & 7) << 4;
            *(int4*)(bsb + byteoff) = *(const int4*)&Bt[(size_t)(bn + r) * K + c];
        }
    }
    __syncthreads();

    f32x4v acc[4][8];
#pragma unroll
    for (int i = 0; i < 4; ++i)
#pragma unroll
        for (int j = 0; j < 8; ++j) acc[i][j] = (f32x4v){0.f, 0.f, 0.f, 0.f};

    const short* aBase = A + (size_t)(row0 + l15) * K + q8;

#pragma unroll
    for (int ks = 0; ks < K / 32; ++ks) {
        bfrag8 af[4], bf[8];
#pragma unroll
        for (int mt = 0; mt < 4; ++mt)
            af[mt] = *(const bfrag8*)(aBase + (size_t)mt * 16 * K + ks * 32);
#pragma unroll
        for (int nt = 0; nt < 8; ++nt) {
            int r = nt * 16 + l15;
            int byteoff = (r * K + ks * 32 + q8) * 2;
            byteoff ^= (r & 7) << 4;
            bf[nt] = *(const bfrag8*)(bsb + byteoff);
        }
#pragma unroll
        for (int mt = 0; mt < 4; ++mt)
#pragma unroll
            for (int nt = 0; nt < 8; ++nt)
                acc[mt][nt] = __builtin_amdgcn_mfma_f32_16x16x32_bf16(af[mt], bf[nt], acc[mt][nt], 0, 0, 0);
    }

#pragma unroll
    for (int mt = 0; mt < 4; ++mt) {
#pragma unroll
        for (int r = 0; r < 4; ++r) {
            int grow = row0 + mt * 16 + quad * 4 + r;
            float di = dinv[grow];
            short* outp = Tout + (size_t)grow * ldt + bn + l15;
#pragma unroll
            for (int nt = 0; nt < 8; ++nt)
                outp[nt * 16] = f2bf(acc[mt][nt][r] * di);
        }
    }
}

// ---------------- csr_fill + layer-1 GEMM, LIGHT co-tenant (R10 lesson) ----------------
// BN=64 tiles (R0-proven acc[4][4] + BSTR=K+8 padded LDS): 34 KB LDS,
// ~116 VGPR, launch_bounds(256,4) -> 4 blocks/CU, so the csr_fill blocks run
// at 1024 threads/CU (2x R7). GEMM re-reads A 4x through L3 but hides under
// the csr atomic pole.

template<int K>
__global__ __launch_bounds__(256, 4) void gemm_csr_kernel(
        const short* __restrict__ A, const short* __restrict__ Bt,
        const float* __restrict__ dinv, short* __restrict__ Tout, int ldt, int tilesX,
        const int* __restrict__ src, const int* __restrict__ dst, int E,
        int* __restrict__ cursor, int* __restrict__ csr, int csrBlocks) {
    constexpr int BSTR = K + 8;
    __shared__ short Bs[64 * BSTR];
    if ((int)blockIdx.x < csrBlocks) {
        int e = blockIdx.x * 256 + threadIdx.x;
        if (e < E) {
            int d = dst[e];
            int p = atomicAdd(&cursor[d], 1);
            csr[p] = src[e];
        }
        return;
    }
    int tile = blockIdx.x - csrBlocks;
    const int bx = tile % tilesX, by = tile / tilesX;

    const int tid = threadIdx.x;
    const int lane = tid & 63;
    const int wid = tid >> 6;
    const int l15 = lane & 15;
    const int quad = lane >> 4;
    const int q8 = quad * 8;
    const int bn = by * 64;
    const int row0 = bx * 256 + wid * 64;

    {
        constexpr int TOT16 = 64 * K / 8;
#pragma unroll
        for (int i = tid; i < TOT16; i += 256) {
            int r = i / (K / 8);
            int c = (i % (K / 8)) * 8;
            *(int4*)&Bs[r * BSTR + c] = *(const int4*)&Bt[(size_t)(bn + r) * K + c];
        }
    }
    __syncthreads();

    f32x4v acc[4][4];
#pragma unroll
    for (int i = 0; i < 4; ++i)
#pragma unroll
        for (int j = 0; j < 4; ++j) acc[i][j] = (f32x4v){0.f, 0.f, 0.f, 0.f};

    const short* aBase = A + (size_t)(row0 + l15) * K + q8;

#pragma unroll
    for (int ks = 0; ks < K / 32; ++ks) {
        bfrag8 af[4], bf[4];
#pragma unroll
        for (int mt = 0; mt < 4; ++mt)
            af[mt] = *(const bfrag8*)(aBase + (size_t)mt * 16 * K + ks * 32);
#pragma unroll
        for (int nt = 0; nt < 4; ++nt)
            bf[nt] = *(const bfrag8*)&Bs[(nt * 16 + l15) * BSTR + ks * 32 + q8];
#pragma unroll
        for (int mt = 0; mt < 4; ++mt)
#pragma unroll
            for (int nt = 0; nt < 4; ++nt)
                acc[mt][nt] = __builtin_amdgcn_mfma_f32_16x16x32_bf16(af[mt], bf[nt], acc[mt][nt], 0, 0, 0);
    }

#pragma unroll
    for (int mt = 0; mt < 4; ++mt) {
#pragma unroll
        for (int r = 0; r < 4; ++r) {
            int grow = row0 + mt * 16 + quad * 4 + r;
            float di = dinv[grow];
            short* outp = Tout + (size_t)grow * ldt + bn + l15;
#pragma unroll
            for (int nt = 0; nt < 4; ++nt)
                outp[nt * 16] = f2bf(acc[mt][nt][r] * di);
        }
    }
}

// ---------------- Aggregation, C=256 ----------------
// One wave per node; 16 B/lane x 32 lanes = one 512 B row; sub=lane>>5 ->
// 2 edges per wave-load, 8 loads in flight. pad16 lists: uniform loop.

template<bool WB>
__global__ __launch_bounds__(256) void agg256_kernel(
        const short* __restrict__ hn, const float* __restrict__ dinv,
        const int* __restrict__ offs, const int* __restrict__ csr,
        const float* __restrict__ bias, float* __restrict__ out,
        short* __restrict__ hb, int coloff, int n) {
    int node = blockIdx.x * 4 + (threadIdx.x >> 6);
    if (node >= n) return;
    int lane = threadIdx.x & 63;
    int hl = lane & 31;        // channel group: 8 ch each
    int sub = lane >> 5;       // edge parity
    const short* base = hn + hl * 8;

    float acc[8];
#pragma unroll
    for (int v = 0; v < 8; ++v) acc[v] = 0.f;

    int beg = offs[node], end = offs[node + 1];
    for (int e = beg + sub; e < end; e += 16) {
        int s[8];
#pragma unroll
        for (int j = 0; j < 8; ++j) s[j] = __builtin_nontemporal_load(csr + e + 2 * j);
        bfrag8 r[8];
#pragma unroll
        for (int j = 0; j < 8; ++j) r[j] = *(const bfrag8*)(base + (size_t)s[j] * 256);
#pragma unroll
        for (int j = 0; j < 8; ++j)
#pragma unroll
            for (int v = 0; v < 8; ++v) acc[v] += bf2f(r[j][v]);
    }

#pragma unroll
    for (int v = 0; v < 8; ++v) acc[v] += __shfl_xor(acc[v], 32);

    if (sub == 0) {
        float di = dinv[node];
        float res[8];
#pragma unroll
        for (int v = 0; v < 8; ++v)
            res[v] = fmaxf(fmaf(di, acc[v], bias[hl * 8 + v]), 0.f);
        float* op = out + (size_t)node * 512 + coloff + hl * 8;
        f32x4v w0 = {res[0], res[1], res[2], res[3]};
        f32x4v w1 = {res[4], res[5], res[6], res[7]};
        __builtin_nontemporal_store(w0, (f32x4v*)op);
        __builtin_nontemporal_store(w1, (f32x4v*)(op + 4));
        if (WB) {
            i32x4v w = {pack2(f2bf(res[0]), f2bf(res[1])), pack2(f2bf(res[2]), f2bf(res[3])),
                        pack2(f2bf(res[4]), f2bf(res[5])), pack2(f2bf(res[6]), f2bf(res[7]))};
            __builtin_nontemporal_store(w, (i32x4v*)(hb + (size_t)node * 256 + hl * 8));
        }
    }
}

// ---------------- Aggregation, C=128 ----------------
// 16 B/lane x 16 lanes = one 256 B row; sub=lane>>4 -> 4 edges per wave-load.
// pad16 lists: 8-deep main loop (32 edges) + single 4-deep 16-edge tail.
// WB path: extended grid zeroes hb pad rows [n, npad) (gemm3 A-pad safety).

template<bool WB>
__global__ __launch_bounds__(256) void agg128_kernel(
        const short* __restrict__ hn, const float* __restrict__ dinv,
        const int* __restrict__ offs, const int* __restrict__ csr,
        const float* __restrict__ bias, float* __restrict__ out,
        short* __restrict__ hb, int coloff, int n, int npad) {
    int node = blockIdx.x * 4 + (threadIdx.x >> 6);
    int lane = threadIdx.x & 63;
    if (node >= n) {
        if (WB && node < npad) ((int*)(hb + (size_t)node * 128))[lane] = 0;
        return;
    }
    int ch = lane & 15;        // channel group: 8 ch each
    int sub = lane >> 4;       // edge slot (4)
    const short* base = hn + ch * 8;

    float acc[8];
#pragma unroll
    for (int v = 0; v < 8; ++v) acc[v] = 0.f;

    int beg = offs[node], end = offs[node + 1];
    int e = beg + sub;
    for (; e + 16 < end; e += 32) {      // 32-edge batch, 8 loads deep
        int s[8];
#pragma unroll
        for (int j = 0; j < 8; ++j) s[j] = __builtin_nontemporal_load(csr + e + 4 * j);
        bfrag8 r[8];
#pragma unroll
        for (int j = 0; j < 8; ++j) r[j] = *(const bfrag8*)(base + (size_t)s[j] * 128);
#pragma unroll
        for (int j = 0; j < 8; ++j)
#pragma unroll
            for (int v = 0; v < 8; ++v) acc[v] += bf2f(r[j][v]);
    }
    if (e < end) {                        // final 16-edge batch, 4 loads deep
        int s[4];
#pragma unroll
        for (int j = 0; j < 4; ++j) s[j] = __builtin_nontemporal_load(csr + e + 4 * j);
        bfrag8 r[4];
#pragma unroll
        for (int j = 0; j < 4; ++j) r[j] = *(const bfrag8*)(base + (size_t)s[j] * 128);
#pragma unroll
        for (int j = 0; j < 4; ++j)
#pragma unroll
            for (int v = 0; v < 8; ++v) acc[v] += bf2f(r[j][v]);
    }

#pragma unroll
    for (int v = 0; v < 8; ++v) {
        acc[v] += __shfl_xor(acc[v], 16);
        acc[v] += __shfl_xor(acc[v], 32);
    }

    if (sub == 0) {
        float di = dinv[node];
        float res[8];
#pragma unroll
        for (int v = 0; v < 8; ++v)
            res[v] = fmaxf(fmaf(di, acc[v], bias[ch * 8 + v]), 0.f);
        float* op = out + (size_t)node * 512 + coloff + ch * 8;
        f32x4v w0 = {res[0], res[1], res[2], res[3]};
        f32x4v w1 = {res[4], res[5], res[6], res[7]};
        __builtin_nontemporal_store(w0, (f32x4v*)op);
        __builtin_nontemporal_store(w1, (f32x4v*)(op + 4));
        if (WB) {
            i32x4v w = {pack2(f2bf(res[0]), f2bf(res[1])), pack2(f2bf(res[2]), f2bf(res[3])),
                        pack2(f2bf(res[4]), f2bf(res[5])), pack2(f2bf(res[6]), f2bf(res[7]))};
            __builtin_nontemporal_store(w, (i32x4v*)(hb + (size_t)node * 128 + ch * 8));
        }
    }
}

// ---------------- launch ----------------

extern "C" void kernel_launch(void* const* d_in, const int* in_sizes, int n_in,
                              void* d_out, int out_size, void* d_ws, size_t ws_size,
                              hipStream_t stream) {
    const float* x  = (const float*)d_in[0];
    const int*   ei = (const int*)d_in[1];
    const float* W1 = (const float*)d_in[2];
    const float* b1 = (const float*)d_in[3];
    const float* W2 = (const float*)d_in[4];
    const float* b2 = (const float*)d_in[5];
    const float* W3 = (const float*)d_in[6];
    const float* b3 = (const float*)d_in[7];

    const int IN_C = 256, H2 = 256, H1 = 128, OUT_C = 128;
    int n = in_sizes[0] / IN_C;   // 50000
    int E = in_sizes[1] / 2;      // 800000
    const int* src = ei;
    const int* dst = ei + E;

    int sb = (n + 255) / 256;     // 196
    int npad = sb * 256;          // 50176

    char* ws = (char*)d_ws;
    auto carve = [&](size_t bytes) { char* p = ws; ws += (bytes + 255) & ~(size_t)255; return p; };
    int*   deg    = (int*)  carve((size_t)n * 4);
    int*   offs   = (int*)  carve(((size_t)n + 1) * 4);
    int*   cursor = (int*)  carve((size_t)n * 4);
    float* dinv   = (float*)carve((size_t)npad * 4);
    int*   csr    = (int*)  carve(((size_t)E + 16 * (size_t)n) * 4);  // self + pad-to-16
    int*   bsums  = (int*)  carve(256 * 4);
    short* Wt1    = (short*)carve((size_t)IN_C * H2 * 2);
    short* Wt2    = (short*)carve((size_t)H2 * H1 * 2);
    short* Wt3    = (short*)carve((size_t)H1 * OUT_C * 2);
    short* xb     = (short*)carve((size_t)npad * 256 * 2);
    short* t      = (short*)carve((size_t)npad * 256 * 2);
    short* inb    = (short*)carve((size_t)npad * 256 * 2);  // h1b -> h2b

    float* out = (float*)d_out;
    int nblk = (n + 255) / 256;   // 196 == sb

    hipMemsetAsync(deg, 0, (size_t)n * sizeof(int), stream);

    // fused deg_count + x->bf16 + W prep (E is a multiple of 256)
    int total8 = n * IN_C / 8;
    int totalp8 = npad * IN_C / 8;     // zero-fill pad rows so t pad rows = 0
    int prepTot = E + totalp8 + 65536 + 32768 + 16384;
    prep_kernel<<<(prepTot + 255) / 256, 256, 0, stream>>>(
        dst, E, deg, x, xb, total8, totalp8, W1, Wt1, W2, Wt2, W3, Wt3);

    block_sum_kernel<<<nblk, 256, 0, stream>>>(deg, n, bsums);
    scan_final_kernel<<<nblk, 256, 0, stream>>>(deg, n, nblk, bsums, offs, cursor, dinv, csr);

    // Layer 1 GEMM (BN=64 light tiles) with csr_fill running concurrently
    int csrBlocks = (E + 255) / 256;              // 3125
    int gemmTiles = sb * (H2 / 64);               // 784
    gemm_csr_kernel<256><<<csrBlocks + gemmTiles, 256, 0, stream>>>(
        xb, Wt1, dinv, t, H2, sb, src, dst, E, cursor, csr, csrBlocks);

    agg256_kernel<true><<<(n + 3) / 4, 256, 0, stream>>>(t, dinv, offs, csr, b1, out, inb, 0, n);

    // Layer 2 (K=256 -> C=128); extended grid zeroes inb's 128-view pad rows
    gemm_skinny_kernel<256><<<dim3(sb, H1 / 128), 256, 0, stream>>>(inb, Wt2, dinv, t, H1);
    agg128_kernel<true><<<(npad + 3) / 4, 256, 0, stream>>>(t, dinv, offs, csr, b2, out, inb, H2, n, npad);

    // Layer 3 (K=128 -> C=128)
    gemm_skinny_kernel<128><<<dim3(sb, OUT_C / 128), 256, 0, stream>>>(inb, Wt3, dinv, t, OUT_C);
    agg128_kernel<false><<<(n + 3) / 4, 256, 0, stream>>>(t, dinv, offs, csr, b3, out, nullptr, H2 + H1, n, npad);
}

// Round 12
// 407.160 us; speedup vs baseline: 1.0208x; 1.0208x over previous
//
#include <hip/hip_runtime.h>

typedef __attribute__((ext_vector_type(8))) short bfrag8;   // 8 bf16 = 4 VGPRs
typedef __attribute__((ext_vector_type(4))) float f32x4v;   // MFMA acc / nt stores
typedef __attribute__((ext_vector_type(4))) int   i32x4v;   // nt stores

__device__ inline short f2bf(float f) {
    unsigned u = __builtin_bit_cast(unsigned, f);
    u = (u + 0x7FFFu + ((u >> 16) & 1u)) >> 16;
    return (short)u;
}
__device__ inline float bf2f(short s) {
    unsigned u = ((unsigned)(unsigned short)s) << 16;
    return __builtin_bit_cast(float, u);
}
__device__ inline int pack2(short lo, short hi) {
    return (int)(((unsigned)(unsigned short)lo) | (((unsigned)(unsigned short)hi) << 16));
}
__device__ inline int pad16i(int v) { return (v + 15) & ~15; }

// ---------------- CSR construction ----------------
// Self-loops folded in (self entry first); lists zero-padded to x16 pointing
// at row n (guaranteed-zero row).
// R5: scatter/atomic kernels: 1 edge/thread-slot + PLAIN stores.
// R8/R9: gather kernels: one-wave-per-node, barrier-free.
// R11: layer-1 GEMM co-tenant must be the BN=128 shape (BN=64 regressed).
// R12 experiment: scatter sections XCD-partitioned by dst range -> cursor/deg/
// csr lines owned by one XCD's L2 (tests line-churn vs atomic-unit bound).

__global__ void block_sum_kernel(const int* __restrict__ deg, int n, int* __restrict__ bsums) {
    int i = blockIdx.x * 256 + threadIdx.x;
    int v = (i < n) ? pad16i(deg[i] + 1) : 0;   // +1 self, padded
#pragma unroll
    for (int off = 32; off > 0; off >>= 1) v += __shfl_down(v, off);
    __shared__ int wsum[4];
    int lane = threadIdx.x & 63, w = threadIdx.x >> 6;
    if (lane == 0) wsum[w] = v;
    __syncthreads();
    if (threadIdx.x == 0) bsums[blockIdx.x] = wsum[0] + wsum[1] + wsum[2] + wsum[3];
}

// Fused: every block redundantly scans the (<=256) block sums in LDS, then
// scans its own 256 padded degrees and emits offs/cursor/dinv/csr-pads.
__global__ void scan_final_kernel(const int* __restrict__ deg, int n, int B,
                                  const int* __restrict__ bsums,
                                  int* __restrict__ offs, int* __restrict__ cursor,
                                  float* __restrict__ dinv, int* __restrict__ csr) {
    __shared__ int sb[256];
    __shared__ int s[256];
    int tid = threadIdx.x;
    sb[tid] = (tid < B) ? bsums[tid] : 0;
    __syncthreads();
    for (int off = 1; off < 256; off <<= 1) {
        int t = (tid >= off) ? sb[tid - off] : 0;
        __syncthreads();
        sb[tid] += t;
        __syncthreads();
    }
    int myBase = (blockIdx.x == 0) ? 0 : sb[blockIdx.x - 1];
    int total = sb[255];
    int i = blockIdx.x * 256 + tid;
    int vt = (i < n) ? deg[i] + 1 : 0;          // true count incl. self
    int pv = (i < n) ? pad16i(vt) : 0;          // padded count
    s[tid] = pv;
    __syncthreads();
    for (int off = 1; off < 256; off <<= 1) {
        int t = (tid >= off) ? s[tid - off] : 0;
        __syncthreads();
        s[tid] += t;
        __syncthreads();
    }
    if (i < n) {
        int excl = s[tid] - pv + myBase;
        offs[i] = excl;
        csr[excl] = i;                           // self-loop first
        cursor[i] = excl + 1;
        for (int p = excl + vt; p < excl + pv; ++p) csr[p] = n;  // zero-row pads
        dinv[i] = rsqrtf((float)vt);
    } else if (i < gridDim.x * 256) {
        dinv[i] = 0.f;                           // pad rows: zero (kills t pads)
    }
    if (blockIdx.x == 0 && tid == 0) offs[n] = total;
}

// ---------------- fused prep: XCD-partitioned deg_count + x->bf16 + W transpose ----------------
// deg section: blocks [0, degBlocks); group g = blockIdx&7 (round-robin = XCD g)
// scans ALL edges (8-deep coalesced stride) but counts only dst in its range
// -> each deg line touched by one XCD. Edge re-reads are L3-streamed.

__global__ void prep_kernel(const int* __restrict__ dst, int E, int* __restrict__ deg,
                            int degBlocks, int range,
                            const float* __restrict__ x, short* __restrict__ xb,
                            int total8, int totalp8,
                            const float* __restrict__ W1, short* __restrict__ Wt1,
                            const float* __restrict__ W2, short* __restrict__ Wt2,
                            const float* __restrict__ W3, short* __restrict__ Wt3) {
    if ((int)blockIdx.x < degBlocks) {
        int g = blockIdx.x & 7;
        int gthreads = (degBlocks >> 3) * 256;
        int base = (blockIdx.x >> 3) * 256 + threadIdx.x;
        int lo = g * range;
#pragma unroll
        for (int it = 0; it < 8; ++it) {
            int e = base + it * gthreads;
            if (e < E) {
                int d = dst[e];
                if ((unsigned)(d - lo) < (unsigned)range) atomicAdd(&deg[d], 1);
            }
        }
        return;
    }
    int i = (blockIdx.x - degBlocks) * 256 + threadIdx.x;
    if (i < total8) {
        const float4* p = (const float4*)(x + (size_t)i * 8);
        float4 v0 = p[0], v1 = p[1];
        int4 w = make_int4(pack2(f2bf(v0.x), f2bf(v0.y)), pack2(f2bf(v0.z), f2bf(v0.w)),
                           pack2(f2bf(v1.x), f2bf(v1.y)), pack2(f2bf(v1.z), f2bf(v1.w)));
        *(int4*)(xb + (size_t)i * 8) = w;
    } else if (i < totalp8) {
        *(int4*)(xb + (size_t)i * 8) = make_int4(0, 0, 0, 0);
    } else {
        int j = i - totalp8;
        if (j < 65536) {                       // W1: K=256, N=256
            int k = j >> 8, c = j & 255;
            Wt1[c * 256 + k] = f2bf(W1[j]);
        } else if (j < 65536 + 32768) {        // W2: K=256, N=128
            int m = j - 65536;
            int k = m >> 7, c = m & 127;
            Wt2[c * 256 + k] = f2bf(W2[m]);
        } else if (j < 65536 + 32768 + 16384) { // W3: K=128, N=128
            int m = j - 65536 - 32768;
            int k = m >> 7, c = m & 127;
            Wt3[c * 128 + k] = f2bf(W3[m]);
        }
    }
}

// ---------------- GEMM core (BN=128, XOR-swizzled B tile in LDS) ----------------

template<int K>
__device__ __forceinline__ void gemm_body(
        const short* __restrict__ A, const short* __restrict__ Bt,
        const float* __restrict__ dinv, short* __restrict__ Tout, int ldt,
        int bx, int by, char* bsb) {
    const int tid = threadIdx.x;
    const int lane = tid & 63;
    const int wid = tid >> 6;
    const int l15 = lane & 15;
    const int quad = lane >> 4;
    const int q8 = quad * 8;
    const int bn = by * 128;
    const int row0 = bx * 256 + wid * 64;

    {
        constexpr int TOT16 = 128 * K / 8;
#pragma unroll
        for (int i = tid; i < TOT16; i += 256) {
            int r = i / (K / 8);
            int c = (i % (K / 8)) * 8;
            int byteoff = (r * K + c) * 2;
            byteoff ^= (r & 7) << 4;
            *(int4*)(bsb + byteoff) = *(const int4*)&Bt[(size_t)(bn + r) * K + c];
        }
    }
    __syncthreads();

    f32x4v acc[4][8];
#pragma unroll
    for (int i = 0; i < 4; ++i)
#pragma unroll
        for (int j = 0; j < 8; ++j) acc[i][j] = (f32x4v){0.f, 0.f, 0.f, 0.f};

    const short* aBase = A + (size_t)(row0 + l15) * K + q8;

#pragma unroll
    for (int ks = 0; ks < K / 32; ++ks) {
        bfrag8 af[4], bf[8];
#pragma unroll
        for (int mt = 0; mt < 4; ++mt)
            af[mt] = *(const bfrag8*)(aBase + (size_t)mt * 16 * K + ks * 32);
#pragma unroll
        for (int nt = 0; nt < 8; ++nt) {
            int r = nt * 16 + l15;
            int byteoff = (r * K + ks * 32 + q8) * 2;
            byteoff ^= (r & 7) << 4;
            bf[nt] = *(const bfrag8*)(bsb + byteoff);
        }
#pragma unroll
        for (int mt = 0; mt < 4; ++mt)
#pragma unroll
            for (int nt = 0; nt < 8; ++nt)
                acc[mt][nt] = __builtin_amdgcn_mfma_f32_16x16x32_bf16(af[mt], bf[nt], acc[mt][nt], 0, 0, 0);
    }

#pragma unroll
    for (int mt = 0; mt < 4; ++mt) {
#pragma unroll
        for (int r = 0; r < 4; ++r) {
            int grow = row0 + mt * 16 + quad * 4 + r;
            float di = dinv[grow];
            short* outp = Tout + (size_t)grow * ldt + bn + l15;
#pragma unroll
            for (int nt = 0; nt < 8; ++nt)
                outp[nt * 16] = f2bf(acc[mt][nt][r] * di);
        }
    }
}

template<int K>
__global__ __launch_bounds__(256, 2) void gemm_skinny_kernel(
        const short* __restrict__ A, const short* __restrict__ Bt,
        const float* __restrict__ dinv, short* __restrict__ Tout, int ldt) {
    __shared__ short Bs[128 * K];
    gemm_body<K>(A, Bt, dinv, Tout, ldt, blockIdx.x, blockIdx.y, (char*)Bs);
}

// Heterogeneous dispatch: blocks [0, csrBlocks) run XCD-partitioned csr_fill;
// the rest run layer-1 GEMM tiles (R7's proven BN=128 shape).
template<int K>
__global__ __launch_bounds__(256, 2) void gemm_csr_kernel(
        const short* __restrict__ A, const short* __restrict__ Bt,
        const float* __restrict__ dinv, short* __restrict__ Tout, int ldt, int tilesX,
        const int* __restrict__ src, const int* __restrict__ dst, int E,
        int* __restrict__ cursor, int* __restrict__ csr, int csrBlocks, int range) {
    __shared__ short Bs[128 * K];
    if ((int)blockIdx.x < csrBlocks) {
        int g = blockIdx.x & 7;
        int gthreads = (csrBlocks >> 3) * 256;
        int base = (blockIdx.x >> 3) * 256 + threadIdx.x;
        int lo = g * range;
#pragma unroll
        for (int it = 0; it < 8; ++it) {
            int e = base + it * gthreads;
            if (e < E) {
                int d = dst[e];
                if ((unsigned)(d - lo) < (unsigned)range) {
                    int p = atomicAdd(&cursor[d], 1);
                    csr[p] = src[e];
                }
            }
        }
        return;
    }
    int tile = blockIdx.x - csrBlocks;
    gemm_body<K>(A, Bt, dinv, Tout, ldt, tile % tilesX, tile / tilesX, (char*)Bs);
}

// ---------------- Aggregation, C=256 ----------------
// One wave per node; 16 B/lane x 32 lanes = one 512 B row; sub=lane>>5 ->
// 2 edges per wave-load, 8 loads in flight. pad16 lists: uniform loop.

template<bool WB>
__global__ __launch_bounds__(256) void agg256_kernel(
        const short* __restrict__ hn, const float* __restrict__ dinv,
        const int* __restrict__ offs, const int* __restrict__ csr,
        const float* __restrict__ bias, float* __restrict__ out,
        short* __restrict__ hb, int coloff, int n) {
    int node = blockIdx.x * 4 + (threadIdx.x >> 6);
    if (node >= n) return;
    int lane = threadIdx.x & 63;
    int hl = lane & 31;        // channel group: 8 ch each
    int sub = lane >> 5;       // edge parity
    const short* base = hn + hl * 8;

    float acc[8];
#pragma unroll
    for (int v = 0; v < 8; ++v) acc[v] = 0.f;

    int beg = offs[node], end = offs[node + 1];
    for (int e = beg + sub; e < end; e += 16) {
        int s[8];
#pragma unroll
        for (int j = 0; j < 8; ++j) s[j] = __builtin_nontemporal_load(csr + e + 2 * j);
        bfrag8 r[8];
#pragma unroll
        for (int j = 0; j < 8; ++j) r[j] = *(const bfrag8*)(base + (size_t)s[j] * 256);
#pragma unroll
        for (int j = 0; j < 8; ++j)
#pragma unroll
            for (int v = 0; v < 8; ++v) acc[v] += bf2f(r[j][v]);
    }

#pragma unroll
    for (int v = 0; v < 8; ++v) acc[v] += __shfl_xor(acc[v], 32);

    if (sub == 0) {
        float di = dinv[node];
        float res[8];
#pragma unroll
        for (int v = 0; v < 8; ++v)
            res[v] = fmaxf(fmaf(di, acc[v], bias[hl * 8 + v]), 0.f);
        float* op = out + (size_t)node * 512 + coloff + hl * 8;
        f32x4v w0 = {res[0], res[1], res[2], res[3]};
        f32x4v w1 = {res[4], res[5], res[6], res[7]};
        __builtin_nontemporal_store(w0, (f32x4v*)op);
        __builtin_nontemporal_store(w1, (f32x4v*)(op + 4));
        if (WB) {
            i32x4v w = {pack2(f2bf(res[0]), f2bf(res[1])), pack2(f2bf(res[2]), f2bf(res[3])),
                        pack2(f2bf(res[4]), f2bf(res[5])), pack2(f2bf(res[6]), f2bf(res[7]))};
            __builtin_nontemporal_store(w, (i32x4v*)(hb + (size_t)node * 256 + hl * 8));
        }
    }
}

// ---------------- Aggregation, C=128 ----------------
// 16 B/lane x 16 lanes = one 256 B row; sub=lane>>4 -> 4 edges per wave-load.
// pad16 lists: 8-deep main loop (32 edges) + single 4-deep 16-edge tail.
// WB path: extended grid zeroes hb pad rows [n, npad) (gemm3 A-pad safety).

template<bool WB>
__global__ __launch_bounds__(256) void agg128_kernel(
        const short* __restrict__ hn, const float* __restrict__ dinv,
        const int* __restrict__ offs, const int* __restrict__ csr,
        const float* __restrict__ bias, float* __restrict__ out,
        short* __restrict__ hb, int coloff, int n, int npad) {
    int node = blockIdx.x * 4 + (threadIdx.x >> 6);
    int lane = threadIdx.x & 63;
    if (node >= n) {
        if (WB && node < npad) ((int*)(hb + (size_t)node * 128))[lane] = 0;
        return;
    }
    int ch = lane & 15;        // channel group: 8 ch each
    int sub = lane >> 4;       // edge slot (4)
    const short* base = hn + ch * 8;

    float acc[8];
#pragma unroll
    for (int v = 0; v < 8; ++v) acc[v] = 0.f;

    int beg = offs[node], end = offs[node + 1];
    int e = beg + sub;
    for (; e + 16 < end; e += 32) {      // 32-edge batch, 8 loads deep
        int s[8];
#pragma unroll
        for (int j = 0; j < 8; ++j) s[j] = __builtin_nontemporal_load(csr + e + 4 * j);
        bfrag8 r[8];
#pragma unroll
        for (int j = 0; j < 8; ++j) r[j] = *(const bfrag8*)(base + (size_t)s[j] * 128);
#pragma unroll
        for (int j = 0; j < 8; ++j)
#pragma unroll
            for (int v = 0; v < 8; ++v) acc[v] += bf2f(r[j][v]);
    }
    if (e < end) {                        // final 16-edge batch, 4 loads deep
        int s[4];
#pragma unroll
        for (int j = 0; j < 4; ++j) s[j] = __builtin_nontemporal_load(csr + e + 4 * j);
        bfrag8 r[4];
#pragma unroll
        for (int j = 0; j < 4; ++j) r[j] = *(const bfrag8*)(base + (size_t)s[j] * 128);
#pragma unroll
        for (int j = 0; j < 4; ++j)
#pragma unroll
            for (int v = 0; v < 8; ++v) acc[v] += bf2f(r[j][v]);
    }

#pragma unroll
    for (int v = 0; v < 8; ++v) {
        acc[v] += __shfl_xor(acc[v], 16);
        acc[v] += __shfl_xor(acc[v], 32);
    }

    if (sub == 0) {
        float di = dinv[node];
        float res[8];
#pragma unroll
        for (int v = 0; v < 8; ++v)
            res[v] = fmaxf(fmaf(di, acc[v], bias[ch * 8 + v]), 0.f);
        float* op = out + (size_t)node * 512 + coloff + ch * 8;
        f32x4v w0 = {res[0], res[1], res[2], res[3]};
        f32x4v w1 = {res[4], res[5], res[6], res[7]};
        __builtin_nontemporal_store(w0, (f32x4v*)op);
        __builtin_nontemporal_store(w1, (f32x4v*)(op + 4));
        if (WB) {
            i32x4v w = {pack2(f2bf(res[0]), f2bf(res[1])), pack2(f2bf(res[2]), f2bf(res[3])),
                        pack2(f2bf(res[4]), f2bf(res[5])), pack2(f2bf(res[6]), f2bf(res[7]))};
            __builtin_nontemporal_store(w, (i32x4v*)(hb + (size_t)node * 128 + ch * 8));
        }
    }
}

// ---------------- launch ----------------

extern "C" void kernel_launch(void* const* d_in, const int* in_sizes, int n_in,
                              void* d_out, int out_size, void* d_ws, size_t ws_size,
                              hipStream_t stream) {
    const float* x  = (const float*)d_in[0];
    const int*   ei = (const int*)d_in[1];
    const float* W1 = (const float*)d_in[2];
    const float* b1 = (const float*)d_in[3];
    const float* W2 = (const float*)d_in[4];
    const float* b2 = (const float*)d_in[5];
    const float* W3 = (const float*)d_in[6];
    const float* b3 = (const float*)d_in[7];

    const int IN_C = 256, H2 = 256, H1 = 128, OUT_C = 128;
    int n = in_sizes[0] / IN_C;   // 50000
    int E = in_sizes[1] / 2;      // 800000
    const int* src = ei;
    const int* dst = ei + E;

    int sb = (n + 255) / 256;     // 196
    int npad = sb * 256;          // 50176

    char* ws = (char*)d_ws;
    auto carve = [&](size_t bytes) { char* p = ws; ws += (bytes + 255) & ~(size_t)255; return p; };
    int*   deg    = (int*)  carve((size_t)n * 4);
    int*   offs   = (int*)  carve(((size_t)n + 1) * 4);
    int*   cursor = (int*)  carve((size_t)n * 4);
    float* dinv   = (float*)carve((size_t)npad * 4);
    int*   csr    = (int*)  carve(((size_t)E + 16 * (size_t)n) * 4);  // self + pad-to-16
    int*   bsums  = (int*)  carve(256 * 4);
    short* Wt1    = (short*)carve((size_t)IN_C * H2 * 2);
    short* Wt2    = (short*)carve((size_t)H2 * H1 * 2);
    short* Wt3    = (short*)carve((size_t)H1 * OUT_C * 2);
    short* xb     = (short*)carve((size_t)npad * 256 * 2);
    short* t      = (short*)carve((size_t)npad * 256 * 2);
    short* inb    = (short*)carve((size_t)npad * 256 * 2);  // h1b -> h2b

    float* out = (float*)d_out;
    int nblk = (n + 255) / 256;   // 196 == sb

    hipMemsetAsync(deg, 0, (size_t)n * sizeof(int), stream);

    // XCD-partitioned scatter geometry: 8 groups, each scans all E edges
    // 8-deep; group g owns dst range [g*range8, (g+1)*range8).
    int range8 = (n + 7) / 8;                       // 6250
    int bpg = (E + 8 * 256 - 1) / (8 * 256);        // blocks per group, 391
    if (bpg < 1) bpg = 1;
    bpg = (bpg + 0);                                // per-group threads = bpg*256
    int degBlocks = ((bpg + 0) * 8);
    // ensure 8 iterations cover E: 8 * bpg*256 >= E
    while (8 * (degBlocks >> 3) * 256 < E) degBlocks += 8;

    // fused partitioned deg_count + x->bf16 + W prep
    int total8 = n * IN_C / 8;
    int totalp8 = npad * IN_C / 8;     // zero-fill pad rows so t pad rows = 0
    int restTot = totalp8 + 65536 + 32768 + 16384;
    int prepBlocks = degBlocks + (restTot + 255) / 256;
    prep_kernel<<<prepBlocks, 256, 0, stream>>>(
        dst, E, deg, degBlocks, range8, x, xb, total8, totalp8,
        W1, Wt1, W2, Wt2, W3, Wt3);

    block_sum_kernel<<<nblk, 256, 0, stream>>>(deg, n, bsums);
    scan_final_kernel<<<nblk, 256, 0, stream>>>(deg, n, nblk, bsums, offs, cursor, dinv, csr);

    // Layer 1 GEMM (R7's proven BN=128 shape) with partitioned csr_fill concurrent
    int csrBlocks = degBlocks;                    // same geometry
    int gemmTiles = sb * (H2 / 128);              // 392
    gemm_csr_kernel<256><<<csrBlocks + gemmTiles, 256, 0, stream>>>(
        xb, Wt1, dinv, t, H2, sb, src, dst, E, cursor, csr, csrBlocks, range8);

    agg256_kernel<true><<<(n + 3) / 4, 256, 0, stream>>>(t, dinv, offs, csr, b1, out, inb, 0, n);

    // Layer 2 (K=256 -> C=128); extended grid zeroes inb's 128-view pad rows
    gemm_skinny_kernel<256><<<dim3(sb, H1 / 128), 256, 0, stream>>>(inb, Wt2, dinv, t, H1);
    agg128_kernel<true><<<(npad + 3) / 4, 256, 0, stream>>>(t, dinv, offs, csr, b2, out, inb, H2, n, npad);

    // Layer 3 (K=128 -> C=128)
    gemm_skinny_kernel<128><<<dim3(sb, OUT_C / 128), 256, 0, stream>>>(inb, Wt3, dinv, t, OUT_C);
    agg128_kernel<false><<<(n + 3) / 4, 256, 0, stream>>>(t, dinv, offs, csr, b3, out, nullptr, H2 + H1, n, npad);
}

// Round 14
// 379.750 us; speedup vs baseline: 1.0944x; 1.0722x over previous
//
#include <hip/hip_runtime.h>

typedef __attribute__((ext_vector_type(8))) short bfrag8;   // 8 bf16 = 4 VGPRs
typedef __attribute__((ext_vector_type(4))) float f32x4v;   // MFMA acc / nt stores
typedef __attribute__((ext_vector_type(4))) int   i32x4v;   // nt stores

__device__ inline short f2bf(float f) {
    unsigned u = __builtin_bit_cast(unsigned, f);
    u = (u + 0x7FFFu + ((u >> 16) & 1u)) >> 16;
    return (short)u;
}
__device__ inline float bf2f(short s) {
    unsigned u = ((unsigned)(unsigned short)s) << 16;
    return __builtin_bit_cast(float, u);
}
__device__ inline int pack2(short lo, short hi) {
    return (int)(((unsigned)(unsigned short)lo) | (((unsigned)(unsigned short)hi) << 16));
}
__device__ inline int pad16i(int v) { return (v + 15) & ~15; }

// ---------------- CSR construction ----------------
// Self-loops folded in (self entry first); lists zero-padded to x16 pointing
// at row n (guaranteed-zero row).
// R5: scatter kernels: 1 edge/thread + PLAIN stores.
// R8/R9: gather kernels: one-wave-per-node, barrier-free.
// R11: layer-1 GEMM co-tenant must be the BN=128 shape.
// R12: csr atomics are RMW-chain bound (not line-churn) -> R13 removes them:
// deg_count's atomicAdd return value IS the edge's rank; csr_fill becomes a
// pure atomic-free scatter csr[offs[dst]+1+rank] = src.

__global__ void block_sum_kernel(const int* __restrict__ deg, int n, int* __restrict__ bsums) {
    int i = blockIdx.x * 256 + threadIdx.x;
    int v = (i < n) ? pad16i(deg[i] + 1) : 0;   // +1 self, padded
#pragma unroll
    for (int off = 32; off > 0; off >>= 1) v += __shfl_down(v, off);
    __shared__ int wsum[4];
    int lane = threadIdx.x & 63, w = threadIdx.x >> 6;
    if (lane == 0) wsum[w] = v;
    __syncthreads();
    if (threadIdx.x == 0) bsums[blockIdx.x] = wsum[0] + wsum[1] + wsum[2] + wsum[3];
}

// Fused: every block redundantly scans the (<=256) block sums in LDS, then
// scans its own 256 padded degrees and emits offs/dinv/csr-pads/self-entries.
__global__ void scan_final_kernel(const int* __restrict__ deg, int n, int B,
                                  const int* __restrict__ bsums,
                                  int* __restrict__ offs,
                                  float* __restrict__ dinv, int* __restrict__ csr) {
    __shared__ int sb[256];
    __shared__ int s[256];
    int tid = threadIdx.x;
    sb[tid] = (tid < B) ? bsums[tid] : 0;
    __syncthreads();
    for (int off = 1; off < 256; off <<= 1) {
        int t = (tid >= off) ? sb[tid - off] : 0;
        __syncthreads();
        sb[tid] += t;
        __syncthreads();
    }
    int myBase = (blockIdx.x == 0) ? 0 : sb[blockIdx.x - 1];
    int total = sb[255];
    int i = blockIdx.x * 256 + tid;
    int vt = (i < n) ? deg[i] + 1 : 0;          // true count incl. self
    int pv = (i < n) ? pad16i(vt) : 0;          // padded count
    s[tid] = pv;
    __syncthreads();
    for (int off = 1; off < 256; off <<= 1) {
        int t = (tid >= off) ? s[tid - off] : 0;
        __syncthreads();
        s[tid] += t;
        __syncthreads();
    }
    if (i < n) {
        int excl = s[tid] - pv + myBase;
        offs[i] = excl;
        csr[excl] = i;                           // self-loop first
        for (int p = excl + vt; p < excl + pv; ++p) csr[p] = n;  // zero-row pads
        dinv[i] = rsqrtf((float)vt);
    } else if (i < gridDim.x * 256) {
        dinv[i] = 0.f;                           // pad rows: zero (kills t pads)
    }
    if (blockIdx.x == 0 && tid == 0) offs[n] = total;
}

// ---------------- fused prep: deg_count(+rank) + x->bf16 (+ zero pads) + W transpose ----------------
// The deg atomicAdd's RETURN VALUE is edge e's rank among same-dst edges;
// storing it (coalesced) lets csr_fill run atomic-free (R13).

__global__ void prep_kernel(const int* __restrict__ dst, int E, int* __restrict__ deg,
                            int* __restrict__ rank,
                            const float* __restrict__ x, short* __restrict__ xb,
                            int total8, int totalp8,
                            const float* __restrict__ W1, short* __restrict__ Wt1,
                            const float* __restrict__ W2, short* __restrict__ Wt2,
                            const float* __restrict__ W3, short* __restrict__ Wt3) {
    int g = blockIdx.x * blockDim.x + threadIdx.x;
    if (g < E) {
        rank[g] = atomicAdd(&deg[dst[g]], 1);
        return;
    }
    int i = g - E;
    if (i < total8) {
        const float4* p = (const float4*)(x + (size_t)i * 8);
        float4 v0 = p[0], v1 = p[1];
        int4 w = make_int4(pack2(f2bf(v0.x), f2bf(v0.y)), pack2(f2bf(v0.z), f2bf(v0.w)),
                           pack2(f2bf(v1.x), f2bf(v1.y)), pack2(f2bf(v1.z), f2bf(v1.w)));
        *(int4*)(xb + (size_t)i * 8) = w;
    } else if (i < totalp8) {
        *(int4*)(xb + (size_t)i * 8) = make_int4(0, 0, 0, 0);
    } else {
        int j = i - totalp8;
        if (j < 65536) {                       // W1: K=256, N=256
            int k = j >> 8, c = j & 255;
            Wt1[c * 256 + k] = f2bf(W1[j]);
        } else if (j < 65536 + 32768) {        // W2: K=256, N=128
            int m = j - 65536;
            int k = m >> 7, c = m & 127;
            Wt2[c * 256 + k] = f2bf(W2[m]);
        } else if (j < 65536 + 32768 + 16384) { // W3: K=128, N=128
            int m = j - 65536 - 32768;
            int k = m >> 7, c = m & 127;
            Wt3[c * 128 + k] = f2bf(W3[m]);
        }
    }
}

// ---------------- GEMM core (BN=128, XOR-swizzled B tile in LDS) ----------------

template<int K>
__device__ __forceinline__ void gemm_body(
        const short* __restrict__ A, const short* __restrict__ Bt,
        const float* __restrict__ dinv, short* __restrict__ Tout, int ldt,
        int bx, int by, char* bsb) {
    const int tid = threadIdx.x;
    const int lane = tid & 63;
    const int wid = tid >> 6;
    const int l15 = lane & 15;
    const int quad = lane >> 4;
    const int q8 = quad * 8;
    const int bn = by * 128;
    const int row0 = bx * 256 + wid * 64;

    {
        constexpr int TOT16 = 128 * K / 8;
#pragma unroll
        for (int i = tid; i < TOT16; i += 256) {
            int r = i / (K / 8);
            int c = (i % (K / 8)) * 8;
            int byteoff = (r * K + c) * 2;
            byteoff ^= (r & 7) << 4;
            *(int4*)(bsb + byteoff) = *(const int4*)&Bt[(size_t)(bn + r) * K + c];
        }
    }
    __syncthreads();

    f32x4v acc[4][8];
#pragma unroll
    for (int i = 0; i < 4; ++i)
#pragma unroll
        for (int j = 0; j < 8; ++j) acc[i][j] = (f32x4v){0.f, 0.f, 0.f, 0.f};

    const short* aBase = A + (size_t)(row0 + l15) * K + q8;

#pragma unroll
    for (int ks = 0; ks < K / 32; ++ks) {
        bfrag8 af[4], bf[8];
#pragma unroll
        for (int mt = 0; mt < 4; ++mt)
            af[mt] = *(const bfrag8*)(aBase + (size_t)mt * 16 * K + ks * 32);
#pragma unroll
        for (int nt = 0; nt < 8; ++nt) {
            int r = nt * 16 + l15;
            int byteoff = (r * K + ks * 32 + q8) * 2;
            byteoff ^= (r & 7) << 4;
            bf[nt] = *(const bfrag8*)(bsb + byteoff);
        }
#pragma unroll
        for (int mt = 0; mt < 4; ++mt)
#pragma unroll
            for (int nt = 0; nt < 8; ++nt)
                acc[mt][nt] = __builtin_amdgcn_mfma_f32_16x16x32_bf16(af[mt], bf[nt], acc[mt][nt], 0, 0, 0);
    }

#pragma unroll
    for (int mt = 0; mt < 4; ++mt) {
#pragma unroll
        for (int r = 0; r < 4; ++r) {
            int grow = row0 + mt * 16 + quad * 4 + r;
            float di = dinv[grow];
            short* outp = Tout + (size_t)grow * ldt + bn + l15;
#pragma unroll
            for (int nt = 0; nt < 8; ++nt)
                outp[nt * 16] = f2bf(acc[mt][nt][r] * di);
        }
    }
}

template<int K>
__global__ __launch_bounds__(256, 2) void gemm_skinny_kernel(
        const short* __restrict__ A, const short* __restrict__ Bt,
        const float* __restrict__ dinv, short* __restrict__ Tout, int ldt) {
    __shared__ short Bs[128 * K];
    gemm_body<K>(A, Bt, dinv, Tout, ldt, blockIdx.x, blockIdx.y, (char*)Bs);
}

// Heterogeneous dispatch: blocks [0, csrBlocks) run the ATOMIC-FREE csr
// scatter (offs+rank precomputed); the rest run layer-1 GEMM tiles.
template<int K>
__global__ __launch_bounds__(256, 2) void gemm_csr_kernel(
        const short* __restrict__ A, const short* __restrict__ Bt,
        const float* __restrict__ dinv, short* __restrict__ Tout, int ldt, int tilesX,
        const int* __restrict__ src, const int* __restrict__ dst, int E,
        const int* __restrict__ offs, const int* __restrict__ rank,
        int* __restrict__ csr, int csrBlocks) {
    __shared__ short Bs[128 * K];
    if ((int)blockIdx.x < csrBlocks) {
        int e = blockIdx.x * 256 + threadIdx.x;
        if (e < E) {
            int d = dst[e];
            int p = offs[d] + 1 + rank[e];   // +1: self-loop sits at offs[d]
            csr[p] = src[e];
        }
        return;
    }
    int tile = blockIdx.x - csrBlocks;
    gemm_body<K>(A, Bt, dinv, Tout, ldt, tile % tilesX, tile / tilesX, (char*)Bs);
}

// ---------------- Aggregation, C=256 ----------------
// One wave per node; 16 B/lane x 32 lanes = one 512 B row; sub=lane>>5 ->
// 2 edges per wave-load, 8 loads in flight. pad16 lists: uniform loop.

template<bool WB>
__global__ __launch_bounds__(256) void agg256_kernel(
        const short* __restrict__ hn, const float* __restrict__ dinv,
        const int* __restrict__ offs, const int* __restrict__ csr,
        const float* __restrict__ bias, float* __restrict__ out,
        short* __restrict__ hb, int coloff, int n) {
    int node = blockIdx.x * 4 + (threadIdx.x >> 6);
    if (node >= n) return;
    int lane = threadIdx.x & 63;
    int hl = lane & 31;        // channel group: 8 ch each
    int sub = lane >> 5;       // edge parity
    const short* base = hn + hl * 8;

    float acc[8];
#pragma unroll
    for (int v = 0; v < 8; ++v) acc[v] = 0.f;

    int beg = offs[node], end = offs[node + 1];
    for (int e = beg + sub; e < end; e += 16) {
        int s[8];
#pragma unroll
        for (int j = 0; j < 8; ++j) s[j] = __builtin_nontemporal_load(csr + e + 2 * j);
        bfrag8 r[8];
#pragma unroll
        for (int j = 0; j < 8; ++j) r[j] = *(const bfrag8*)(base + (size_t)s[j] * 256);
#pragma unroll
        for (int j = 0; j < 8; ++j)
#pragma unroll
            for (int v = 0; v < 8; ++v) acc[v] += bf2f(r[j][v]);
    }

#pragma unroll
    for (int v = 0; v < 8; ++v) acc[v] += __shfl_xor(acc[v], 32);

    if (sub == 0) {
        float di = dinv[node];
        float res[8];
#pragma unroll
        for (int v = 0; v < 8; ++v)
            res[v] = fmaxf(fmaf(di, acc[v], bias[hl * 8 + v]), 0.f);
        float* op = out + (size_t)node * 512 + coloff + hl * 8;
        f32x4v w0 = {res[0], res[1], res[2], res[3]};
        f32x4v w1 = {res[4], res[5], res[6], res[7]};
        __builtin_nontemporal_store(w0, (f32x4v*)op);
        __builtin_nontemporal_store(w1, (f32x4v*)(op + 4));
        if (WB) {
            i32x4v w = {pack2(f2bf(res[0]), f2bf(res[1])), pack2(f2bf(res[2]), f2bf(res[3])),
                        pack2(f2bf(res[4]), f2bf(res[5])), pack2(f2bf(res[6]), f2bf(res[7]))};
            __builtin_nontemporal_store(w, (i32x4v*)(hb + (size_t)node * 256 + hl * 8));
        }
    }
}

// ---------------- Aggregation, C=128 ----------------
// 16 B/lane x 16 lanes = one 256 B row; sub=lane>>4 -> 4 edges per wave-load.
// pad16 lists: 8-deep main loop (32 edges) + single 4-deep 16-edge tail.
// WB path: extended grid zeroes hb pad rows [n, npad) (gemm3 A-pad safety).

template<bool WB>
__global__ __launch_bounds__(256) void agg128_kernel(
        const short* __restrict__ hn, const float* __restrict__ dinv,
        const int* __restrict__ offs, const int* __restrict__ csr,
        const float* __restrict__ bias, float* __restrict__ out,
        short* __restrict__ hb, int coloff, int n, int npad) {
    int node = blockIdx.x * 4 + (threadIdx.x >> 6);
    int lane = threadIdx.x & 63;
    if (node >= n) {
        if (WB && node < npad) ((int*)(hb + (size_t)node * 128))[lane] = 0;
        return;
    }
    int ch = lane & 15;        // channel group: 8 ch each
    int sub = lane >> 4;       // edge slot (4)
    const short* base = hn + ch * 8;

    float acc[8];
#pragma unroll
    for (int v = 0; v < 8; ++v) acc[v] = 0.f;

    int beg = offs[node], end = offs[node + 1];
    int e = beg + sub;
    for (; e + 16 < end; e += 32) {      // 32-edge batch, 8 loads deep
        int s[8];
#pragma unroll
        for (int j = 0; j < 8; ++j) s[j] = __builtin_nontemporal_load(csr + e + 4 * j);
        bfrag8 r[8];
#pragma unroll
        for (int j = 0; j < 8; ++j) r[j] = *(const bfrag8*)(base + (size_t)s[j] * 128);
#pragma unroll
        for (int j = 0; j < 8; ++j)
#pragma unroll
            for (int v = 0; v < 8; ++v) acc[v] += bf2f(r[j][v]);
    }
    if (e < end) {                        // final 16-edge batch, 4 loads deep
        int s[4];
#pragma unroll
        for (int j = 0; j < 4; ++j) s[j] = __builtin_nontemporal_load(csr + e + 4 * j);
        bfrag8 r[4];
#pragma unroll
        for (int j = 0; j < 4; ++j) r[j] = *(const bfrag8*)(base + (size_t)s[j] * 128);
#pragma unroll
        for (int j = 0; j < 4; ++j)
#pragma unroll
            for (int v = 0; v < 8; ++v) acc[v] += bf2f(r[j][v]);
    }

#pragma unroll
    for (int v = 0; v < 8; ++v) {
        acc[v] += __shfl_xor(acc[v], 16);
        acc[v] += __shfl_xor(acc[v], 32);
    }

    if (sub == 0) {
        float di = dinv[node];
        float res[8];
#pragma unroll
        for (int v = 0; v < 8; ++v)
            res[v] = fmaxf(fmaf(di, acc[v], bias[ch * 8 + v]), 0.f);
        float* op = out + (size_t)node * 512 + coloff + ch * 8;
        f32x4v w0 = {res[0], res[1], res[2], res[3]};
        f32x4v w1 = {res[4], res[5], res[6], res[7]};
        __builtin_nontemporal_store(w0, (f32x4v*)op);
        __builtin_nontemporal_store(w1, (f32x4v*)(op + 4));
        if (WB) {
            i32x4v w = {pack2(f2bf(res[0]), f2bf(res[1])), pack2(f2bf(res[2]), f2bf(res[3])),
                        pack2(f2bf(res[4]), f2bf(res[5])), pack2(f2bf(res[6]), f2bf(res[7]))};
            __builtin_nontemporal_store(w, (i32x4v*)(hb + (size_t)node * 128 + ch * 8));
        }
    }
}

// ---------------- launch ----------------

extern "C" void kernel_launch(void* const* d_in, const int* in_sizes, int n_in,
                              void* d_out, int out_size, void* d_ws, size_t ws_size,
                              hipStream_t stream) {
    const float* x  = (const float*)d_in[0];
    const int*   ei = (const int*)d_in[1];
    const float* W1 = (const float*)d_in[2];
    const float* b1 = (const float*)d_in[3];
    const float* W2 = (const float*)d_in[4];
    const float* b2 = (const float*)d_in[5];
    const float* W3 = (const float*)d_in[6];
    const float* b3 = (const float*)d_in[7];

    const int IN_C = 256, H2 = 256, H1 = 128, OUT_C = 128;
    int n = in_sizes[0] / IN_C;   // 50000
    int E = in_sizes[1] / 2;      // 800000
    const int* src = ei;
    const int* dst = ei + E;

    int sb = (n + 255) / 256;     // 196
    int npad = sb * 256;          // 50176

    char* ws = (char*)d_ws;
    auto carve = [&](size_t bytes) { char* p = ws; ws += (bytes + 255) & ~(size_t)255; return p; };
    int*   deg    = (int*)  carve((size_t)n * 4);
    int*   offs   = (int*)  carve(((size_t)n + 1) * 4);
    int*   rank   = (int*)  carve((size_t)E * 4);
    float* dinv   = (float*)carve((size_t)npad * 4);
    int*   csr    = (int*)  carve(((size_t)E + 16 * (size_t)n) * 4);  // self + pad-to-16
    int*   bsums  = (int*)  carve(256 * 4);
    short* Wt1    = (short*)carve((size_t)IN_C * H2 * 2);
    short* Wt2    = (short*)carve((size_t)H2 * H1 * 2);
    short* Wt3    = (short*)carve((size_t)H1 * OUT_C * 2);
    short* xb     = (short*)carve((size_t)npad * 256 * 2);
    short* t      = (short*)carve((size_t)npad * 256 * 2);
    short* inb    = (short*)carve((size_t)npad * 256 * 2);  // h1b -> h2b

    float* out = (float*)d_out;
    int nblk = (n + 255) / 256;   // 196 == sb

    hipMemsetAsync(deg, 0, (size_t)n * sizeof(int), stream);

    // fused deg_count(+rank) + x->bf16 + W prep (E is a multiple of 256)
    int total8 = n * IN_C / 8;
    int totalp8 = npad * IN_C / 8;     // zero-fill pad rows so t pad rows = 0
    int prepTot = E + totalp8 + 65536 + 32768 + 16384;
    prep_kernel<<<(prepTot + 255) / 256, 256, 0, stream>>>(
        dst, E, deg, rank, x, xb, total8, totalp8, W1, Wt1, W2, Wt2, W3, Wt3);

    block_sum_kernel<<<nblk, 256, 0, stream>>>(deg, n, bsums);
    scan_final_kernel<<<nblk, 256, 0, stream>>>(deg, n, nblk, bsums, offs, dinv, csr);

    // Layer 1 GEMM with ATOMIC-FREE csr scatter running concurrently
    int csrBlocks = (E + 255) / 256;              // 3125
    int gemmTiles = sb * (H2 / 128);              // 392
    gemm_csr_kernel<256><<<csrBlocks + gemmTiles, 256, 0, stream>>>(
        xb, Wt1, dinv, t, H2, sb, src, dst, E, offs, rank, csr, csrBlocks);

    agg256_kernel<true><<<(n + 3) / 4, 256, 0, stream>>>(t, dinv, offs, csr, b1, out, inb, 0, n);

    // Layer 2 (K=256 -> C=128); extended grid zeroes inb's 128-view pad rows
    gemm_skinny_kernel<256><<<dim3(sb, H1 / 128), 256, 0, stream>>>(inb, Wt2, dinv, t, H1);
    agg128_kernel<true><<<(npad + 3) / 4, 256, 0, stream>>>(t, dinv, offs, csr, b2, out, inb, H2, n, npad);

    // Layer 3 (K=128 -> C=128)
    gemm_skinny_kernel<128><<<dim3(sb, OUT_C / 128), 256, 0, stream>>>(inb, Wt3, dinv, t, OUT_C);
    agg128_kernel<false><<<(n + 3) / 4, 256, 0, stream>>>(t, dinv, offs, csr, b3, out, nullptr, H2 + H1, n, npad);
}